// Round 1
// baseline (1080.893 us; speedup 1.0000x reference)
//
#include <hip/hip_runtime.h>

#define BB 8
#define NN 1024
#define CC 64
#define TT 12
#define OO 64

// ---- workspace layout (floats) ----
static constexpr size_t XT_OFF  = 0;
static constexpr size_t XT_SZ   = (size_t)TT*BB*NN*CC;   // x transposed [T,B,N,C]
static constexpr size_t DE1_OFF = XT_OFF + XT_SZ;
static constexpr size_t DE_SZ   = (size_t)TT*BB*NN*OO;   // [T,B,N,O]
static constexpr size_t DE2_OFF = DE1_OFF + DE_SZ;
static constexpr size_t RS_OFF  = DE2_OFF + DE_SZ;       // rowsum [T,B,N]
static constexpr size_t RS_SZ   = (size_t)TT*BB*NN;
static constexpr size_t M_OFF   = RS_OFF + RS_SZ;        // M/A chunk [tc,B,N,N]
static constexpr size_t M_PER_T = (size_t)BB*NN*NN;

// K0: x [B,N,C,T] -> xt [T,B,N,C]
__global__ __launch_bounds__(256) void k0_transpose(const float* __restrict__ x,
                                                    float* __restrict__ xt) {
  const int n = blockIdx.x, b = blockIdx.y;
  __shared__ float s[CC*TT];
  const float* src = x + (size_t)(b*NN + n)*CC*TT;
  for (int k = threadIdx.x; k < CC*TT; k += 256) s[k] = src[k];
  __syncthreads();
  for (int k = threadIdx.x; k < CC*TT; k += 256) {
    const int t = k >> 6, c = k & 63;
    xt[(((size_t)t*BB + b)*NN + n)*CC + c] = s[c*TT + t];
  }
}

// K1: base = xt@Wd[t] + bd[t]; DE1 = tanh(base*E1); DE2 = tanh(base*E2)
__global__ __launch_bounds__(256) void k1_base(const float* __restrict__ xt,
    const float* __restrict__ Wd, const float* __restrict__ bd,
    const float* __restrict__ E1, const float* __restrict__ E2,
    float* __restrict__ DE1, float* __restrict__ DE2) {
  const int tile = blockIdx.x;            // 64 tiles of 16 rows
  const int b = blockIdx.y, t = blockIdx.z;
  __shared__ float Wds[CC*OO];
  __shared__ float xs[16*CC];
  const float* Wdt = Wd + (size_t)t*CC*OO;
  for (int k = threadIdx.x; k < CC*OO; k += 256) Wds[k] = Wdt[k];
  const size_t xbase = (((size_t)t*BB + b)*NN + tile*16)*CC;
  for (int k = threadIdx.x; k < 16*CC; k += 256) xs[k] = xt[xbase + k];
  __syncthreads();
  const int o = threadIdx.x & 63, rr = threadIdx.x >> 6;
  for (int r = rr; r < 16; r += 4) {
    float acc = bd[t*OO + o];
    #pragma unroll
    for (int c = 0; c < CC; ++c) acc = fmaf(xs[r*CC + c], Wds[c*OO + o], acc);
    const int n = tile*16 + r;
    const size_t eo = ((size_t)t*NN + n)*OO + o;
    const size_t so = (((size_t)t*BB + b)*NN + n)*OO + o;
    DE1[so] = tanhf(acc * E1[eo]);
    DE2[so] = tanhf(acc * E2[eo]);
  }
}

__global__ __launch_bounds__(256) void k_init_rowsum(float* __restrict__ rs) {
  const size_t i = (size_t)blockIdx.x*256 + threadIdx.x;
  if (i < RS_SZ) rs[i] = 1.0f;   // +I contribution to degree
}

// K2: M = DE1 @ DE2^T  (64x64 output tiles, K=64)
__global__ __launch_bounds__(256) void k2_M(const float* __restrict__ DE1,
    const float* __restrict__ DE2, float* __restrict__ Mbuf, int t0) {
  const int ti = blockIdx.x >> 4, tj = blockIdx.x & 15;
  const int b = blockIdx.y, tl = blockIdx.z, t = t0 + tl;
  __shared__ __align__(16) float d1[64*65];
  __shared__ __align__(16) float d2[64*65];
  const size_t dbase = ((size_t)t*BB + b)*NN*OO;
  const float* p1 = DE1 + dbase + (size_t)ti*64*OO;
  const float* p2 = DE2 + dbase + (size_t)tj*64*OO;
  for (int k = threadIdx.x*4; k < 4096; k += 1024) {
    const int r = k >> 6, c = k & 63;
    const float4 v1 = *(const float4*)(p1 + r*OO + c);
    const float4 v2 = *(const float4*)(p2 + r*OO + c);
    d1[r*65+c+0]=v1.x; d1[r*65+c+1]=v1.y; d1[r*65+c+2]=v1.z; d1[r*65+c+3]=v1.w;
    d2[r*65+c+0]=v2.x; d2[r*65+c+1]=v2.y; d2[r*65+c+2]=v2.z; d2[r*65+c+3]=v2.w;
  }
  __syncthreads();
  const int tx = threadIdx.x & 15, ty = threadIdx.x >> 4;
  float acc[4][4] = {};
  #pragma unroll 8
  for (int o = 0; o < 64; ++o) {
    float a[4], bv[4];
    #pragma unroll
    for (int u = 0; u < 4; ++u) a[u]  = d1[(ty*4+u)*65 + o];
    #pragma unroll
    for (int v = 0; v < 4; ++v) bv[v] = d2[(tx*4+v)*65 + o];
    #pragma unroll
    for (int u = 0; u < 4; ++u)
      #pragma unroll
      for (int v = 0; v < 4; ++v)
        acc[u][v] = fmaf(a[u], bv[v], acc[u][v]);
  }
  float* mp = Mbuf + ((size_t)tl*BB + b)*NN*NN + (size_t)(ti*64 + ty*4)*NN + tj*64 + tx*4;
  #pragma unroll
  for (int u = 0; u < 4; ++u) {
    float4 v; v.x=acc[u][0]; v.y=acc[u][1]; v.z=acc[u][2]; v.w=acc[u][3];
    *(float4*)(mp + (size_t)u*NN) = v;
  }
}

// K3: A = relu(tanh(M - M^T)) in place (pair tiles), rowsum += per-row sums
__global__ __launch_bounds__(256) void k3_A(float* __restrict__ Mbuf,
    float* __restrict__ rowsum, int t0) {
  int pp = blockIdx.x;
  const int b = blockIdx.y, tl = blockIdx.z, t = t0 + tl;
  int ti = 0, tj = 0;
  for (ti = 0; ti < 16; ++ti) { const int cnt = 16 - ti; if (pp < cnt) { tj = ti + pp; break; } pp -= cnt; }
  const bool diag = (ti == tj);
  __shared__ __align__(16) float mij[64*65];
  __shared__ __align__(16) float mji[64*65];
  float* Mb = Mbuf + ((size_t)tl*BB + b)*NN*NN;
  for (int k = threadIdx.x*4; k < 4096; k += 1024) {
    const int r = k >> 6, c = k & 63;
    const float4 v = *(const float4*)(Mb + (size_t)(ti*64+r)*NN + tj*64 + c);
    mij[r*65+c+0]=v.x; mij[r*65+c+1]=v.y; mij[r*65+c+2]=v.z; mij[r*65+c+3]=v.w;
    if (!diag) {
      const float4 w = *(const float4*)(Mb + (size_t)(tj*64+r)*NN + ti*64 + c);
      mji[r*65+c+0]=w.x; mji[r*65+c+1]=w.y; mji[r*65+c+2]=w.z; mji[r*65+c+3]=w.w;
    }
  }
  __syncthreads();
  const int tx = threadIdx.x & 15, ty = threadIdx.x >> 4;
  const float* mjip = diag ? mij : mji;
  float aij[4][4], aji[4][4];
  #pragma unroll
  for (int u = 0; u < 4; ++u)
    #pragma unroll
    for (int v = 0; v < 4; ++v) {
      const float z  = mij[(ty*4+u)*65 + tx*4+v] - mjip[(tx*4+v)*65 + ty*4+u];
      const float tz = tanhf(z);
      aij[u][v] = fmaxf(tz, 0.0f);
      aji[u][v] = fmaxf(-tz, 0.0f);
    }
  float* rs = rowsum + ((size_t)t*BB + b)*NN;
  #pragma unroll
  for (int u = 0; u < 4; ++u) {       // rows of the (ti) side: reduce over tx
    float s = aij[u][0]+aij[u][1]+aij[u][2]+aij[u][3];
    s += __shfl_xor(s, 1); s += __shfl_xor(s, 2);
    s += __shfl_xor(s, 4); s += __shfl_xor(s, 8);
    if ((threadIdx.x & 15) == 0) atomicAdd(&rs[ti*64 + ty*4 + u], s);
  }
  if (!diag) {
    #pragma unroll
    for (int v = 0; v < 4; ++v) {     // rows of the (tj) side: reduce over ty within wave
      float s = aji[0][v]+aji[1][v]+aji[2][v]+aji[3][v];
      s += __shfl_xor(s, 16); s += __shfl_xor(s, 32);
      if ((threadIdx.x & 63) < 16) atomicAdd(&rs[tj*64 + tx*4 + v], s);
    }
  }
  {
    float* mp = Mb + (size_t)(ti*64 + ty*4)*NN + tj*64 + tx*4;
    #pragma unroll
    for (int u = 0; u < 4; ++u) {
      float4 v; v.x=aij[u][0]; v.y=aij[u][1]; v.z=aij[u][2]; v.w=aij[u][3];
      *(float4*)(mp + (size_t)u*NN) = v;
    }
  }
  if (!diag) {
    __syncthreads();                 // everyone done reading mij/mji
    #pragma unroll
    for (int u = 0; u < 4; ++u)
      #pragma unroll
      for (int v = 0; v < 4; ++v)
        mji[(tx*4+v)*65 + ty*4+u] = aji[u][v];   // transpose in LDS
    __syncthreads();
    for (int k = threadIdx.x*4; k < 4096; k += 1024) {
      const int r = k >> 6, c = k & 63;
      float4 v; v.x=mji[r*65+c]; v.y=mji[r*65+c+1]; v.z=mji[r*65+c+2]; v.w=mji[r*65+c+3];
      *(float4*)(Mb + (size_t)(tj*64+r)*NN + ti*64 + c) = v;
    }
  }
}

// K4: dagg = dinv_i*(A@ (dinv_j*x)) + dinv_i^2*x ; sagg = adj@x ;
//     out = 0.475*(dagg@Wd+bd) + 0.475*(sagg@Ws+bs) + 0.05*(x@W0+b0)
__global__ __launch_bounds__(256) void k4_out(const float* __restrict__ Abuf,
    const float* __restrict__ xt, const float* __restrict__ adj,
    const float* __restrict__ rowsum,
    const float* __restrict__ Wd, const float* __restrict__ Ws,
    const float* __restrict__ W0, const float* __restrict__ bd,
    const float* __restrict__ bs, const float* __restrict__ b0,
    float* __restrict__ out, int t0) {
  const int ti = blockIdx.x, b = blockIdx.y, tl = blockIdx.z, t = t0 + tl;
  __shared__ __align__(16) float As[64*68];   // transposed [m][row], pad 68 (b128-aligned)
  __shared__ __align__(16) float Js[64*68];   // adj transposed, reused as weight buf
  __shared__ __align__(16) float Xs[64*64];   // [m][c]
  const int tx = threadIdx.x & 15, ty = threadIdx.x >> 4;
  const float* Ab = Abuf + ((size_t)tl*BB + b)*NN*NN;
  const float* xb = xt + (((size_t)t*BB + b)*NN)*CC;
  const float* rs = rowsum + ((size_t)t*BB + b)*NN;
  const int i0 = ti*64;
  float accd[4][4] = {}; float accs[4][4] = {};
  for (int tj = 0; tj < 16; ++tj) {
    const int j0 = tj*64;
    __syncthreads();
    for (int k = threadIdx.x*4; k < 4096; k += 1024) {
      const int r = k >> 6, c = k & 63;
      const float4 a4 = *(const float4*)(Ab + (size_t)(i0+r)*NN + j0 + c);
      const float4 r4 = *(const float4*)(rs + j0 + c);
      const float4 j4 = *(const float4*)(adj + (size_t)(i0+r)*NN + j0 + c);
      const float4 x4 = *(const float4*)(xb + (size_t)(j0+r)*CC + c);
      As[(c+0)*68 + r] = a4.x * rsqrtf(r4.x);
      As[(c+1)*68 + r] = a4.y * rsqrtf(r4.y);
      As[(c+2)*68 + r] = a4.z * rsqrtf(r4.z);
      As[(c+3)*68 + r] = a4.w * rsqrtf(r4.w);
      Js[(c+0)*68 + r] = j4.x; Js[(c+1)*68 + r] = j4.y;
      Js[(c+2)*68 + r] = j4.z; Js[(c+3)*68 + r] = j4.w;
      *(float4*)&Xs[r*64 + c] = x4;
    }
    __syncthreads();
    #pragma unroll 8
    for (int m = 0; m < 64; ++m) {
      const float4 bx = *(const float4*)&Xs[m*64 + tx*4];
      const float4 aA = *(const float4*)&As[m*68 + ty*4];
      const float4 aJ = *(const float4*)&Js[m*68 + ty*4];
      const float av[4] = {aA.x, aA.y, aA.z, aA.w};
      const float jv[4] = {aJ.x, aJ.y, aJ.z, aJ.w};
      const float bv[4] = {bx.x, bx.y, bx.z, bx.w};
      #pragma unroll
      for (int u = 0; u < 4; ++u)
        #pragma unroll
        for (int v = 0; v < 4; ++v) {
          accd[u][v] = fmaf(av[u], bv[v], accd[u][v]);
          accs[u][v] = fmaf(jv[u], bv[v], accs[u][v]);
        }
    }
  }
  // ---- final combine: 3 passes through (src @ W) with shared-buffer reuse ----
  __syncthreads();
  for (int k = threadIdx.x*4; k < 4096; k += 1024) {   // Xs <- xt i-tile
    const int r = k >> 6, c = k & 63;
    *(float4*)&Xs[r*64 + c] = *(const float4*)(xb + (size_t)(i0+r)*CC + c);
  }
  for (int k = threadIdx.x; k < 4096; k += 256) Js[k] = 0.475f * Wd[(size_t)t*4096 + k];
  __syncthreads();
  #pragma unroll
  for (int u = 0; u < 4; ++u) {       // src <- dagg (with dinv scaling + identity)
    const int n = ty*4 + u;
    const float di = rsqrtf(rs[i0 + n]);
    #pragma unroll
    for (int v = 0; v < 4; ++v)
      As[n*65 + tx*4 + v] = di*accd[u][v] + di*di*Xs[n*64 + tx*4 + v];
  }
  __syncthreads();
  float oacc[4][4] = {};
#define ACCUM_PASS() do { \
    _Pragma("unroll 8") \
    for (int c2 = 0; c2 < 64; ++c2) { \
      const float4 w4 = *(const float4*)&Js[c2*64 + tx*4]; \
      const float wv[4] = {w4.x, w4.y, w4.z, w4.w}; \
      float sv[4]; \
      _Pragma("unroll") \
      for (int u = 0; u < 4; ++u) sv[u] = As[(ty*4+u)*65 + c2]; \
      _Pragma("unroll") \
      for (int u = 0; u < 4; ++u) \
        _Pragma("unroll") \
        for (int v = 0; v < 4; ++v) \
          oacc[u][v] = fmaf(sv[u], wv[v], oacc[u][v]); \
    } } while (0)
  ACCUM_PASS();
  __syncthreads();
  #pragma unroll
  for (int u = 0; u < 4; ++u)         // src <- sagg
    #pragma unroll
    for (int v = 0; v < 4; ++v)
      As[(ty*4+u)*65 + tx*4 + v] = accs[u][v];
  for (int k = threadIdx.x; k < 4096; k += 256) Js[k] = 0.475f * Ws[(size_t)t*4096 + k];
  __syncthreads();
  ACCUM_PASS();
  __syncthreads();
  for (int k = threadIdx.x; k < 4096; k += 256) {  // src <- x tile ; W <- 0.05*W0
    As[(k>>6)*65 + (k&63)] = Xs[k];
    Js[k] = 0.05f * W0[k];
  }
  __syncthreads();
  ACCUM_PASS();
#undef ACCUM_PASS
  #pragma unroll
  for (int v = 0; v < 4; ++v) {
    const int o = tx*4 + v;
    const float bias = 0.475f*bs[t*OO + o] + 0.475f*bd[t*OO + o] + 0.05f*b0[o];
    #pragma unroll
    for (int u = 0; u < 4; ++u) {
      const int n = i0 + ty*4 + u;
      out[((size_t)((size_t)b*NN + n)*OO + o)*TT + t] = oacc[u][v] + bias;
    }
  }
}

extern "C" void kernel_launch(void* const* d_in, const int* in_sizes, int n_in,
                              void* d_out, int out_size, void* d_ws, size_t ws_size,
                              hipStream_t stream) {
  const float* x   = (const float*)d_in[0];
  const float* adj = (const float*)d_in[1];
  const float* W0  = (const float*)d_in[2];
  const float* b0  = (const float*)d_in[3];
  const float* Ws  = (const float*)d_in[4];
  const float* bs  = (const float*)d_in[5];
  const float* Wd  = (const float*)d_in[6];
  const float* bd  = (const float*)d_in[7];
  const float* E1  = (const float*)d_in[8];
  const float* E2  = (const float*)d_in[9];
  float* out = (float*)d_out;
  float* ws  = (float*)d_ws;

  float* xt   = ws + XT_OFF;
  float* DE1  = ws + DE1_OFF;
  float* DE2  = ws + DE2_OFF;
  float* rsum = ws + RS_OFF;
  float* Mbuf = ws + M_OFF;

  // how many timesteps of M fit in the remaining workspace
  const size_t ws_floats = ws_size / 4;
  size_t avail = (ws_floats > M_OFF) ? (ws_floats - M_OFF) : 0;
  int tc = (int)(avail / M_PER_T);
  if (tc < 1) tc = 1;
  if (tc > TT) tc = TT;

  k0_transpose<<<dim3(NN, BB), 256, 0, stream>>>(x, xt);
  k1_base<<<dim3(64, BB, TT), 256, 0, stream>>>(xt, Wd, bd, E1, E2, DE1, DE2);
  k_init_rowsum<<<dim3((unsigned)((RS_SZ + 255)/256)), 256, 0, stream>>>(rsum);

  for (int t0 = 0; t0 < TT; t0 += tc) {
    const int nt = (t0 + tc <= TT) ? tc : (TT - t0);
    k2_M  <<<dim3(256, BB, nt), 256, 0, stream>>>(DE1, DE2, Mbuf, t0);
    k3_A  <<<dim3(136, BB, nt), 256, 0, stream>>>(Mbuf, rsum, t0);
    k4_out<<<dim3(16,  BB, nt), 256, 0, stream>>>(Mbuf, xt, adj, rsum,
                                                  Wd, Ws, W0, bd, bs, b0, out, t0);
  }
}

// Round 2
// 383.100 us; speedup vs baseline: 2.8214x; 2.8214x over previous
//
#include <hip/hip_runtime.h>

#define BB 8
#define NN 1024
#define CC 64
#define TT 12
#define OO 64

typedef unsigned short u16;
typedef __attribute__((ext_vector_type(8))) short s16x8;
typedef __attribute__((ext_vector_type(4))) float f32x4;
typedef __attribute__((ext_vector_type(4))) unsigned short u16x4;

__device__ __forceinline__ u16 f2bu(float f){
  union { float f; unsigned u; } v; v.f = f;
  unsigned r = v.u + 0x7FFFu + ((v.u >> 16) & 1u);
  return (u16)(r >> 16);
}
__device__ __forceinline__ float b2f(u16 h){
  union { unsigned u; float f; } v; v.u = ((unsigned)h) << 16; return v.f;
}
__device__ __forceinline__ float tanh_pos(float x){   // x >= 0
  float e = __expf(2.0f * x);
  return 1.0f - 2.0f * __builtin_amdgcn_rcpf(e + 1.0f);
}
__device__ __forceinline__ float tanh_sgn(float x){
  float t = tanh_pos(fabsf(x));
  return x < 0.0f ? -t : t;
}

#define MFMA16(a,b,c) __builtin_amdgcn_mfma_f32_16x16x32_bf16((a),(b),(c),0,0,0)

// frag load from padded-72 row-major LDS tile (row stride 144B = 9x16B, aligned)
__device__ __forceinline__ s16x8 ld72(const u16* s, int row0, int ko, int lane){
  return *(const s16x8*)(s + (row0 + (lane & 15)) * 72 + ko + ((lane >> 4) << 3));
}
// frag load from XOR-swizzled 128x64 bf16 tile (row stride 128B)
__device__ __forceinline__ s16x8 ldsw(const u16* s, int row0, int ko, int lane){
  const int row = row0 + (lane & 15);
  int byte = (row << 7) + ((ko + ((lane >> 4) << 3)) << 1);
  byte ^= (row & 7) << 4;
  return *(const s16x8*)((const char*)s + byte);
}

// ---------------- K0: x [B,N,C,T] f32 -> xt [T,B,N,C] bf16 ----------------
__global__ __launch_bounds__(256) void k0_transpose(const float* __restrict__ x,
                                                    u16* __restrict__ xt){
  const int n = blockIdx.x, b = blockIdx.y;
  __shared__ float s[CC*TT];
  const float* src = x + (size_t)(b*NN + n)*CC*TT;
  for (int k = threadIdx.x; k < CC*TT; k += 256) s[k] = src[k];
  __syncthreads();
  for (int k = threadIdx.x; k < CC*TT; k += 256){
    const int t = k >> 6, c = k & 63;
    xt[(((size_t)t*BB + b)*NN + n)*CC + c] = f2bu(s[c*TT + t]);
  }
}

// ---------------- kadj: adj f32 -> bf16 ----------------
__global__ __launch_bounds__(256) void kadj(const float* __restrict__ adj,
                                            u16* __restrict__ adjb){
  const size_t i = ((size_t)blockIdx.x*256 + threadIdx.x)*4;
  const float4 v = *(const float4*)(adj + i);
  u16x4 o; o[0]=f2bu(v.x); o[1]=f2bu(v.y); o[2]=f2bu(v.z); o[3]=f2bu(v.w);
  *(u16x4*)(adjb + i) = o;
}

// ---------------- kinit: rowsum = 1 (identity contribution) ----------------
__global__ __launch_bounds__(256) void kinit(float* __restrict__ rs){
  const size_t i = (size_t)blockIdx.x*256 + threadIdx.x;
  if (i < (size_t)TT*BB*NN) rs[i] = 1.0f;
}

// ---------------- K1: base = xt@Wd + bd; DE1/2 = tanh(base*E1/2) bf16 ------
__global__ __launch_bounds__(256) void k1_de(const u16* __restrict__ xt,
    const float* __restrict__ Wd, const float* __restrict__ bd,
    const float* __restrict__ E1, const float* __restrict__ E2,
    u16* __restrict__ DE1g, u16* __restrict__ DE2g){
  __shared__ u16 sWd[64*72], sE1[64*72], sE2[64*72], sX[64*72];
  const int tid = threadIdx.x, lane = tid & 63, wid = tid >> 6;
  const int it = blockIdx.x, t = blockIdx.y;
  const int n0 = it * 64;
  for (int k = tid; k < 4096; k += 256){
    const int o = k & 63, c = k >> 6;
    sWd[o*72 + c] = f2bu(Wd[(size_t)t*4096 + c*64 + o]);   // transposed [o][c]
  }
  for (int k = tid; k < 4096; k += 256){
    const int r = k >> 6, o = k & 63;
    const size_t idx = ((size_t)t*NN + n0 + r)*OO + o;
    sE1[r*72 + o] = f2bu(E1[idx]);
    sE2[r*72 + o] = f2bu(E2[idx]);
  }
  float bdv[4];
  #pragma unroll
  for (int v = 0; v < 4; ++v) bdv[v] = bd[t*OO + v*16 + (lane & 15)];
  __syncthreads();
  const int wrow = wid * 16;
  const f32x4 fz = {0.f,0.f,0.f,0.f};
  for (int b = 0; b < BB; ++b){
    const u16* gx = xt + (((size_t)t*BB + b)*NN + n0)*CC;
    for (int k = tid; k < 512; k += 256){
      const int r = k >> 3, c = (k & 7) << 3;
      *(s16x8*)(sX + r*72 + c) = *(const s16x8*)(gx + r*CC + c);
    }
    __syncthreads();
    f32x4 acc[4] = {fz, fz, fz, fz};
    #pragma unroll
    for (int ks = 0; ks < 2; ++ks){
      const int ko = ks*32;
      const s16x8 a = ld72(sX, wrow, ko, lane);
      #pragma unroll
      for (int v = 0; v < 4; ++v)
        acc[v] = MFMA16(a, ld72(sWd, v*16, ko, lane), acc[v]);
    }
    #pragma unroll
    for (int v = 0; v < 4; ++v){
      const int o = v*16 + (lane & 15);
      #pragma unroll
      for (int e = 0; e < 4; ++e){
        const int row = wrow + ((lane >> 4) << 2) + e;
        const float base = acc[v][e] + bdv[v];
        const size_t dst = (((size_t)t*BB + b)*NN + n0 + row)*OO + o;
        DE1g[dst] = f2bu(tanh_sgn(base * b2f(sE1[row*72 + o])));
        DE2g[dst] = f2bu(tanh_sgn(base * b2f(sE2[row*72 + o])));
      }
    }
    __syncthreads();
  }
}

// ------- K23: fused M build + antisym + tanh/relu + rowsum, A in bf16 -------
// pair tile (ti,tj), 128x128. Z1 = DE1_i*DE2_j^T, Z2 = DE2_i*DE1_j^T.
// A_ij = relu(tanh(Z1-Z2)); A_ji = relu(tanh(Z2-Z1))^T.
__global__ __launch_bounds__(256) void k23(const u16* __restrict__ DE1g,
    const u16* __restrict__ DE2g, u16* __restrict__ Abuf,
    float* __restrict__ rowsum, int t0){
  __shared__ u16 sbuf[4*128*64];   // 64 KiB; later aliased as 128x128 Q/P tile
  u16* s1i = sbuf;
  u16* s2j = sbuf + 8192;
  u16* s2i = sbuf + 16384;
  u16* s1j = sbuf + 24576;
  const int tid = threadIdx.x, lane = tid & 63, wid = tid >> 6;
  int pp = blockIdx.x, ti = 0, tj = 0;
  for (ti = 0; ti < 8; ++ti){ const int cnt = 8 - ti; if (pp < cnt){ tj = ti + pp; break; } pp -= cnt; }
  const int b = blockIdx.y, t = t0 + blockIdx.z;
  const size_t tb = (size_t)t*BB + b;
  const u16* g1i = DE1g + (tb*NN + (size_t)ti*128)*OO;
  const u16* g2i = DE2g + (tb*NN + (size_t)ti*128)*OO;
  const u16* g1j = DE1g + (tb*NN + (size_t)tj*128)*OO;
  const u16* g2j = DE2g + (tb*NN + (size_t)tj*128)*OO;
  for (int k = tid; k < 1024; k += 256){
    const int r = k >> 3, cb = (k & 7) << 4;           // byte col
    int byte = (r << 7) + cb; byte ^= (r & 7) << 4;
    *(s16x8*)((char*)s1i + byte) = *(const s16x8*)(g1i + r*OO + (cb >> 1));
    *(s16x8*)((char*)s2i + byte) = *(const s16x8*)(g2i + r*OO + (cb >> 1));
    *(s16x8*)((char*)s1j + byte) = *(const s16x8*)(g1j + r*OO + (cb >> 1));
    *(s16x8*)((char*)s2j + byte) = *(const s16x8*)(g2j + r*OO + (cb >> 1));
  }
  __syncthreads();
  const int ro = (wid >> 1) * 64, co = (wid & 1) * 64;
  const f32x4 fz = {0.f,0.f,0.f,0.f};
  f32x4 z1[4][4], z2[4][4];
  #pragma unroll
  for (int u = 0; u < 4; ++u)
    #pragma unroll
    for (int v = 0; v < 4; ++v){ z1[u][v] = fz; z2[u][v] = fz; }
  #pragma unroll
  for (int ks = 0; ks < 2; ++ks){
    const int ko = ks * 32;
    s16x8 b1[4], b2[4];
    #pragma unroll
    for (int v = 0; v < 4; ++v){
      b1[v] = ldsw(s2j, co + v*16, ko, lane);
      b2[v] = ldsw(s1j, co + v*16, ko, lane);
    }
    #pragma unroll
    for (int u = 0; u < 4; ++u){
      const s16x8 a1 = ldsw(s1i, ro + u*16, ko, lane);
      const s16x8 a2 = ldsw(s2i, ro + u*16, ko, lane);
      #pragma unroll
      for (int v = 0; v < 4; ++v){
        z1[u][v] = MFMA16(a1, b1[v], z1[u][v]);
        z2[u][v] = MFMA16(a2, b2[v], z2[u][v]);
      }
    }
  }
  // elementwise: q = relu(tanh(d)), p = relu(tanh(-d)); partial row/col sums
  float rowp[4][4]; float colp[4] = {0.f,0.f,0.f,0.f};
  #pragma unroll
  for (int u = 0; u < 4; ++u){ rowp[u][0]=rowp[u][1]=rowp[u][2]=rowp[u][3]=0.f; }
  #pragma unroll
  for (int u = 0; u < 4; ++u)
    #pragma unroll
    for (int v = 0; v < 4; ++v)
      #pragma unroll
      for (int e = 0; e < 4; ++e){
        const float d = z1[u][v][e] - z2[u][v][e];
        const float tt = tanh_pos(fabsf(d));
        const float q = d > 0.f ? tt : 0.f;
        const float p = tt - q;
        z1[u][v][e] = q; z2[u][v][e] = p;
        rowp[u][e] += q; colp[v] += p;
      }
  float* rsg = rowsum + tb*NN;
  #pragma unroll
  for (int u = 0; u < 4; ++u)
    #pragma unroll
    for (int e = 0; e < 4; ++e){
      float r = rowp[u][e];
      r += __shfl_xor(r, 1); r += __shfl_xor(r, 2);
      r += __shfl_xor(r, 4); r += __shfl_xor(r, 8);
      if ((lane & 15) == 0)
        atomicAdd(&rsg[ti*128 + ro + u*16 + ((lane >> 4) << 2) + e], r);
    }
  if (ti != tj){
    #pragma unroll
    for (int v = 0; v < 4; ++v){
      float c = colp[v];
      c += __shfl_xor(c, 16); c += __shfl_xor(c, 32);
      if ((lane >> 4) == 0)
        atomicAdd(&rsg[tj*128 + co + v*16 + lane], c);
    }
  }
  // Q tile through LDS (swizzled 128x128 bf16), coalesced store
  u16* sQP = sbuf;
  u16* Ag = Abuf + ((size_t)blockIdx.z * BB + b) * NN * NN;
  __syncthreads();
  #pragma unroll
  for (int u = 0; u < 4; ++u)
    #pragma unroll
    for (int v = 0; v < 4; ++v)
      #pragma unroll
      for (int e = 0; e < 4; ++e){
        const int rl = ro + u*16 + ((lane >> 4) << 2) + e;
        const int cl = co + v*16 + (lane & 15);
        int byte = (rl << 8) + (cl << 1); byte ^= (rl & 7) << 4;
        *(u16*)((char*)sQP + byte) = f2bu(z1[u][v][e]);
      }
  __syncthreads();
  for (int k = tid; k < 2048; k += 256){
    const int r = k >> 4, cb = (k & 15) << 4;
    int byte = (r << 8) + cb; byte ^= (r & 7) << 4;
    *(s16x8*)(Ag + (size_t)(ti*128 + r)*NN + tj*128 + (cb >> 1)) =
        *(const s16x8*)((const char*)sQP + byte);
  }
  if (ti != tj){
    __syncthreads();
    #pragma unroll
    for (int u = 0; u < 4; ++u)
      #pragma unroll
      for (int v = 0; v < 4; ++v)
        #pragma unroll
        for (int e = 0; e < 4; ++e){
          const int rl = ro + u*16 + ((lane >> 4) << 2) + e;
          const int cl = co + v*16 + (lane & 15);
          int byte = (cl << 8) + (rl << 1); byte ^= (cl & 7) << 4;   // transposed
          *(u16*)((char*)sQP + byte) = f2bu(z2[u][v][e]);
        }
    __syncthreads();
    for (int k = tid; k < 2048; k += 256){
      const int r = k >> 4, cb = (k & 15) << 4;
      int byte = (r << 8) + cb; byte ^= (r & 7) << 4;
      *(s16x8*)(Ag + (size_t)(tj*128 + r)*NN + ti*128 + (cb >> 1)) =
          *(const s16x8*)((const char*)sQP + byte);
    }
  }
}

// ---- K3b: xdw' = 0.475*dis*x@Wd ; xsw' = 0.475*x@Ws ; x0w = 0.05*x@W0+bias
//      all stored TRANSPOSED [t][b][o][n] bf16 for use as MFMA B operands ----
__global__ __launch_bounds__(256) void k3b(const u16* __restrict__ xt,
    const float* __restrict__ Wd, const float* __restrict__ Ws,
    const float* __restrict__ W0, const float* __restrict__ bd,
    const float* __restrict__ bs, const float* __restrict__ b0,
    const float* __restrict__ rowsum, u16* __restrict__ xdwT,
    u16* __restrict__ xswT, u16* __restrict__ x0wT, int t0){
  __shared__ u16 sX[128*72];
  __shared__ u16 sW[3][64*72];
  const int tid = threadIdx.x, lane = tid & 63, wid = tid >> 6;
  const int it = blockIdx.x, b = blockIdx.y, t = t0 + blockIdx.z;
  const size_t tb = (size_t)t*BB + b;
  const int n0 = it * 128;
  for (int k = tid; k < 4096; k += 256){
    const int o = k & 63, c = k >> 6;
    sW[0][o*72 + c] = f2bu(0.475f * Wd[(size_t)t*4096 + c*64 + o]);
    sW[1][o*72 + c] = f2bu(0.475f * Ws[(size_t)t*4096 + c*64 + o]);
    sW[2][o*72 + c] = f2bu(0.05f  * W0[c*64 + o]);
  }
  const u16* gx = xt + (tb*NN + n0)*CC;
  for (int k = tid; k < 1024; k += 256){
    const int r = k >> 3, c = (k & 7) << 3;
    *(s16x8*)(sX + r*72 + c) = *(const s16x8*)(gx + r*CC + c);
  }
  __syncthreads();
  const int wrow = wid * 32;
  const float* rsb = rowsum + tb*NN + n0;
  float dis[2][4];
  #pragma unroll
  for (int u = 0; u < 2; ++u)
    #pragma unroll
    for (int e = 0; e < 4; ++e)
      dis[u][e] = rsqrtf(rsb[wrow + u*16 + ((lane >> 4) << 2) + e]);
  float badd[4];
  #pragma unroll
  for (int v = 0; v < 4; ++v){
    const int o = v*16 + (lane & 15);
    badd[v] = 0.475f*(bd[t*OO + o] + bs[t*OO + o]) + 0.05f*b0[o];
  }
  const f32x4 fz = {0.f,0.f,0.f,0.f};
  for (int pass = 0; pass < 3; ++pass){
    f32x4 acc[2][4];
    #pragma unroll
    for (int u = 0; u < 2; ++u)
      #pragma unroll
      for (int v = 0; v < 4; ++v) acc[u][v] = fz;
    #pragma unroll
    for (int ks = 0; ks < 2; ++ks){
      const int ko = ks*32;
      s16x8 bw[4];
      #pragma unroll
      for (int v = 0; v < 4; ++v) bw[v] = ld72(sW[pass], v*16, ko, lane);
      #pragma unroll
      for (int u = 0; u < 2; ++u){
        const s16x8 a = ld72(sX, wrow + u*16, ko, lane);
        #pragma unroll
        for (int v = 0; v < 4; ++v) acc[u][v] = MFMA16(a, bw[v], acc[u][v]);
      }
    }
    u16* dst = (pass == 0) ? xdwT : ((pass == 1) ? xswT : x0wT);
    #pragma unroll
    for (int u = 0; u < 2; ++u)
      #pragma unroll
      for (int v = 0; v < 4; ++v){
        const int o = v*16 + (lane & 15);
        const int nl = n0 + wrow + u*16 + ((lane >> 4) << 2);
        u16x4 pk;
        #pragma unroll
        for (int e = 0; e < 4; ++e){
          float val = acc[u][v][e];
          if (pass == 0) val *= dis[u][e];
          if (pass == 2) val += badd[v];
          pk[e] = f2bu(val);
        }
        *(u16x4*)(dst + (tb*OO + o)*NN + nl) = pk;
      }
  }
}

// ---- K4: outT = dis_i*(A@xdw' + xdw'_i) + adj@xsw' + x0w  (all MFMA) ----
__global__ __launch_bounds__(256) void k4(const u16* __restrict__ Abuf,
    const u16* __restrict__ adjb, const u16* __restrict__ xdwT,
    const u16* __restrict__ xswT, const u16* __restrict__ x0wT,
    const float* __restrict__ rowsum, float* __restrict__ outT, int t0){
  __shared__ u16 sA[128*72], sJ[128*72], sD[64*72], sS[64*72];
  const int tid = threadIdx.x, lane = tid & 63, wid = tid >> 6;
  const int it = blockIdx.x, b = blockIdx.y, tl = blockIdx.z, t = t0 + tl;
  const size_t tb = (size_t)t*BB + b;
  const u16* Ag = Abuf + ((size_t)tl*BB + b)*NN*NN;
  const int i0 = it * 128;
  const int wrow = wid * 32;
  const f32x4 fz = {0.f,0.f,0.f,0.f};
  f32x4 ad[2][4], as_[2][4];
  #pragma unroll
  for (int u = 0; u < 2; ++u)
    #pragma unroll
    for (int v = 0; v < 4; ++v){ ad[u][v] = fz; as_[u][v] = fz; }
  for (int tj = 0; tj < 16; ++tj){
    const int j0 = tj * 64;
    __syncthreads();
    for (int k = tid; k < 1024; k += 256){
      const int r = k >> 3, c = (k & 7) << 3;
      *(s16x8*)(sA + r*72 + c) = *(const s16x8*)(Ag + (size_t)(i0 + r)*NN + j0 + c);
      *(s16x8*)(sJ + r*72 + c) = *(const s16x8*)(adjb + (size_t)(i0 + r)*NN + j0 + c);
    }
    for (int k = tid; k < 512; k += 256){
      const int r = k >> 3, c = (k & 7) << 3;
      *(s16x8*)(sD + r*72 + c) = *(const s16x8*)(xdwT + (tb*OO + r)*NN + j0 + c);
      *(s16x8*)(sS + r*72 + c) = *(const s16x8*)(xswT + (tb*OO + r)*NN + j0 + c);
    }
    __syncthreads();
    #pragma unroll
    for (int ks = 0; ks < 2; ++ks){
      const int ko = ks*32;
      s16x8 bD[4], bS[4];
      #pragma unroll
      for (int v = 0; v < 4; ++v){
        bD[v] = ld72(sD, v*16, ko, lane);
        bS[v] = ld72(sS, v*16, ko, lane);
      }
      #pragma unroll
      for (int u = 0; u < 2; ++u){
        const s16x8 aA = ld72(sA, wrow + u*16, ko, lane);
        const s16x8 aJ = ld72(sJ, wrow + u*16, ko, lane);
        #pragma unroll
        for (int v = 0; v < 4; ++v){
          ad[u][v]  = MFMA16(aA, bD[v], ad[u][v]);
          as_[u][v] = MFMA16(aJ, bS[v], as_[u][v]);
        }
      }
    }
  }
  const float* rsb = rowsum + tb*NN + i0;
  float dis[2][4];
  #pragma unroll
  for (int u = 0; u < 2; ++u)
    #pragma unroll
    for (int e = 0; e < 4; ++e)
      dis[u][e] = rsqrtf(rsb[wrow + u*16 + ((lane >> 4) << 2) + e]);
  #pragma unroll
  for (int u = 0; u < 2; ++u)
    #pragma unroll
    for (int v = 0; v < 4; ++v){
      const int o = v*16 + (lane & 15);
      const int nl = i0 + wrow + u*16 + ((lane >> 4) << 2);
      const u16x4 xv = *(const u16x4*)(xdwT + (tb*OO + o)*NN + nl);
      const u16x4 zv = *(const u16x4*)(x0wT + (tb*OO + o)*NN + nl);
      #pragma unroll
      for (int e = 0; e < 4; ++e){
        const float val = dis[u][e]*(ad[u][v][e] + b2f(xv[e])) + as_[u][v][e] + b2f(zv[e]);
        outT[(tb*NN + nl + e)*OO + o] = val;
      }
    }
}

// ---------------- K5: outT [T,B,N,O] -> out [B,N,O,T], coalesced ----------
__global__ __launch_bounds__(256) void k5(const float* __restrict__ outT,
                                          float* __restrict__ out){
  __shared__ float s[16*64*12];
  const int tid = threadIdx.x;
  const int nb = blockIdx.x, b = blockIdx.y;
  const int n0 = nb * 16;
  for (int t = 0; t < TT; ++t){
    for (int k = tid; k < 1024; k += 256){
      const int r = k >> 6, o = k & 63;
      s[(r*64 + o)*12 + t] = outT[(((size_t)t*BB + b)*NN + n0 + r)*OO + o];
    }
  }
  __syncthreads();
  float* dst = out + (size_t)(b*NN + n0)*OO*TT;
  for (int k = tid; k < 16*64*12; k += 256) dst[k] = s[k];
}

extern "C" void kernel_launch(void* const* d_in, const int* in_sizes, int n_in,
                              void* d_out, int out_size, void* d_ws, size_t ws_size,
                              hipStream_t stream) {
  const float* x   = (const float*)d_in[0];
  const float* adj = (const float*)d_in[1];
  const float* W0  = (const float*)d_in[2];
  const float* b0  = (const float*)d_in[3];
  const float* Ws  = (const float*)d_in[4];
  const float* bs  = (const float*)d_in[5];
  const float* Wd  = (const float*)d_in[6];
  const float* bd  = (const float*)d_in[7];
  const float* E1  = (const float*)d_in[8];
  const float* E2  = (const float*)d_in[9];
  float* out = (float*)d_out;

  char* w = (char*)d_ws;
  size_t off = 0;
  auto take = [&](size_t bytes) -> char* {
    char* p = w + off;
    off += bytes; off = (off + 255) & ~(size_t)255;
    return p;
  };
  const size_t NE = (size_t)TT*BB*NN*OO;     // 6,291,456
  u16*   xt    = (u16*)  take(NE*2);
  u16*   adjb  = (u16*)  take((size_t)NN*NN*2);
  u16*   DE1   = (u16*)  take(NE*2);
  u16*   DE2   = (u16*)  take(NE*2);
  float* rowsum= (float*)take((size_t)TT*BB*NN*4);
  u16*   xdwT  = (u16*)  take(NE*2);
  u16*   xswT  = (u16*)  take(NE*2);
  u16*   x0wT  = (u16*)  take(NE*2);
  float* outT  = (float*)take(NE*4);
  const size_t perT = (size_t)BB*NN*NN*2;
  size_t rem = (ws_size > off) ? (ws_size - off) : 0;
  int tc = (int)(rem / perT);
  if (tc < 1) tc = 1;
  if (tc > TT) tc = TT;
  u16* Abuf = (u16*)(w + off);

  k0_transpose<<<dim3(NN, BB), 256, 0, stream>>>(x, xt);
  kadj<<<dim3((NN*NN)/1024), 256, 0, stream>>>(adj, adjb);
  k1_de<<<dim3(16, TT), 256, 0, stream>>>(xt, Wd, bd, E1, E2, DE1, DE2);
  kinit<<<dim3((TT*BB*NN + 255)/256), 256, 0, stream>>>(rowsum);

  for (int t0 = 0; t0 < TT; t0 += tc){
    const int nt = (t0 + tc <= TT) ? tc : (TT - t0);
    k23<<<dim3(36, BB, nt), 256, 0, stream>>>(DE1, DE2, Abuf, rowsum, t0);
    k3b<<<dim3(8, BB, nt), 256, 0, stream>>>(xt, Wd, Ws, W0, bd, bs, b0,
                                             rowsum, xdwT, xswT, x0wT, t0);
    k4 <<<dim3(8, BB, nt), 256, 0, stream>>>(Abuf, adjb, xdwT, xswT, x0wT,
                                             rowsum, outT, t0);
  }
  k5<<<dim3(NN/16, BB), 256, 0, stream>>>(outT, out);
}